// Round 1
// baseline (723.115 us; speedup 1.0000x reference)
//
#include <hip/hip_runtime.h>
#include <math.h>

// ---------- small vector helpers ----------
struct V3 { float x, y, z; };
__device__ __forceinline__ V3 v3(float a, float b, float c){ V3 r; r.x=a; r.y=b; r.z=c; return r; }
__device__ __forceinline__ V3 vsub(V3 a, V3 b){ return v3(a.x-b.x, a.y-b.y, a.z-b.z); }
__device__ __forceinline__ float vdot(V3 a, V3 b){ return a.x*b.x + a.y*b.y + a.z*b.z; }
__device__ __forceinline__ V3 vcross(V3 a, V3 b){
  return v3(a.y*b.z - a.z*b.y, a.z*b.x - a.x*b.z, a.x*b.y - a.y*b.x);
}
__device__ __forceinline__ V3 vunit(V3 a){            // reference _normalize: x / max(|x|, 1e-12)
  float n = sqrtf(vdot(a,a));
  float inv = 1.0f / fmaxf(n, 1e-12f);
  return v3(a.x*inv, a.y*inv, a.z*inv);
}
__device__ __forceinline__ float sgnf(float x){ return (x > 0.f) ? 1.f : ((x < 0.f) ? -1.f : 0.f); }
__device__ __forceinline__ float bcastf(float v, int lane){   // v_readlane (SGPR lane index ok)
  return __int_as_float(__builtin_amdgcn_readlane(__float_as_int(v), lane));
}

// ---------- setup: Gram matrices for analytic LayerNorm stats ----------
// A_e = [W_edge(23x128); b_edge] (24x128):  Ge[i][j] = (1/128) * dot(A_i, A_j),  abarE[k] = rowmean(A_k)
// A_n = [W_node(4x128);  b_node] (5x128):   Gn, abarN likewise.
__global__ void setup_gram(const float* __restrict__ Wn, const float* __restrict__ bn,
                           const float* __restrict__ We, const float* __restrict__ be,
                           float* __restrict__ Ge, float* __restrict__ abarE,
                           float* __restrict__ Gn, float* __restrict__ abarN)
{
  int tid = threadIdx.x;
  if (tid < 576) {
    int i = tid / 24, j = tid % 24;
    const float* ai = (i < 23) ? (We + i * 128) : be;
    const float* aj = (j < 23) ? (We + j * 128) : be;
    float s = 0.f;
    for (int c = 0; c < 128; ++c) s += ai[c] * aj[c];
    Ge[tid] = s * (1.0f / 128.0f);
  } else if (tid < 601) {
    int t = tid - 576; int i = t / 5, j = t % 5;
    const float* ai = (i < 4) ? (Wn + i * 128) : bn;
    const float* aj = (j < 4) ? (Wn + j * 128) : bn;
    float s = 0.f;
    for (int c = 0; c < 128; ++c) s += ai[c] * aj[c];
    Gn[t] = s * (1.0f / 128.0f);
  } else if (tid < 625) {
    int k = tid - 601;
    const float* a = (k < 23) ? (We + k * 128) : be;
    float s = 0.f;
    for (int c = 0; c < 128; ++c) s += a[c];
    abarE[k] = s * (1.0f / 128.0f);
  } else if (tid < 630) {
    int k = tid - 625;
    const float* a = (k < 4) ? (Wn + k * 128) : bn;
    float s = 0.f;
    for (int c = 0; c < 128; ++c) s += a[c];
    abarN[k] = s * (1.0f / 128.0f);
  }
}

// ---------- node kernel: h_V + stage Q/valid ----------
// wave handles 64 nodes; lane = node for feature phase, lane = column pair for matmul phase.
__global__ __launch_bounds__(256) void node_kernel(
    const float* __restrict__ X, const int* __restrict__ batch,
    const float* __restrict__ Wn, const float* __restrict__ bn,
    const float* __restrict__ gn, const float* __restrict__ betan,
    const float* __restrict__ Gn, const float* __restrict__ abarN,
    float* __restrict__ Qws, int* __restrict__ validws,
    float* __restrict__ outV, int N)
{
  int lane = threadIdx.x & 63;
  int wave = threadIdx.x >> 6;
  int base = blockIdx.x * 256 + wave * 64;
  int i = base + lane;
  bool live = (i < N);
  int ic = live ? i : (N - 1);

  int im1 = (ic >= 1) ? ic - 1 : 0;
  int ip1 = (ic + 1 < N) ? ic + 1 : N - 1;
  int ip2 = (ic + 2 < N) ? ic + 2 : N - 1;

  V3 xm1 = v3(X[3*im1], X[3*im1+1], X[3*im1+2]);
  V3 x0  = v3(X[3*ic ], X[3*ic +1], X[3*ic +2]);
  V3 xp1 = v3(X[3*ip1], X[3*ip1+1], X[3*ip1+2]);
  V3 xp2 = v3(X[3*ip2], X[3*ip2+1], X[3*ip2+2]);

  int b0 = batch[ic];
  bool bnd_i  = (ic >= 1)    && (batch[ic - 1] != b0);
  bool bnd_i1 = (ic + 1 < N) && (batch[ic + 1] != b0);
  bool bnd_i2 = (ic + 2 < N) && (batch[ic + 2] != batch[ic + 1]);

  bool bad_d = bnd_i || bnd_i1 || bnd_i2 || (ic == 0) || (ic >= N - 2);
  bool bad_a = bnd_i || bnd_i1 || (ic == 0) || (ic == N - 1);

  V3 u0 = vunit(vsub(x0,  xm1));   // U[i-1]
  V3 u1 = vunit(vsub(xp1, x0 ));   // U[i]
  V3 u2 = vunit(vsub(xp2, xp1));   // U[i+1]
  V3 c1 = vunit(vcross(u0, u1));
  V3 c2 = vunit(vcross(u1, u2));

  float cosd = vdot(c1, c2);
  cosd = fminf(fmaxf(cosd, -1.0f + 1e-6f), 1.0f - 1e-6f);
  float sd = vdot(c2, u0);
  // sin(arccos(c)*sign) = sign*sqrt(1-c^2); cos(...) = c; sign==0 -> dih=0 -> (0,1)
  float f0, f1;
  if (bad_d)          { f0 = 0.f; f1 = 0.f; }
  else {
    float sg = sgnf(sd);
    if (sg == 0.f)    { f0 = 0.f; f1 = 1.f; }
    else              { f0 = sg * sqrtf(fmaxf(1.f - cosd * cosd, 0.f)); f1 = cosd; }
  }

  V3 d0 = vunit(vsub(xm1, x0));
  V3 d1 = vunit(vsub(xp1, x0));
  float cosa = vdot(d0, d1);
  float sina = sqrtf(fmaxf(1.0f - cosa * cosa + 1e-6f, 0.f));
  float f2 = bad_a ? 0.f : sina;
  float f3 = bad_a ? 0.f : cosa;

  // local frame Q (columns: bvec, nvec, bvec x nvec), zeroed when bad_a
  V3 bv = vunit(vsub(u0, u1));
  V3 nv = c1;                       // == unit(cross(u0,u1))
  V3 tv = vcross(bv, nv);
  float q[9];
  if (bad_a) {
    #pragma unroll
    for (int k = 0; k < 9; ++k) q[k] = 0.f;
  } else {
    q[0]=bv.x; q[1]=nv.x; q[2]=tv.x;
    q[3]=bv.y; q[4]=nv.y; q[5]=tv.y;
    q[6]=bv.z; q[7]=nv.z; q[8]=tv.z;
  }
  if (live) {
    #pragma unroll
    for (int k = 0; k < 9; ++k) Qws[(size_t)i * 9 + k] = q[k];
    validws[i] = bad_a ? 0 : 1;
  }

  // analytic LN stats: fa = [f0..f3, 1]
  float fa[5] = { f0, f1, f2, f3, 1.0f };
  float mmean = 0.f;
  #pragma unroll
  for (int k = 0; k < 5; ++k) mmean = fmaf(fa[k], abarN[k], mmean);
  float E2 = 0.f;
  #pragma unroll
  for (int ii = 0; ii < 5; ++ii) {
    float ti = 0.f;
    #pragma unroll
    for (int jj = 0; jj < 5; ++jj) ti = fmaf(Gn[ii * 5 + jj], fa[jj], ti);
    E2 = fmaf(fa[ii], ti, E2);
  }
  float var  = fmaxf(E2 - mmean * mmean, 0.f);
  float rstd = rsqrtf(var + 1e-5f);

  // per-lane output columns
  float W0[4], W1[4];
  #pragma unroll
  for (int k = 0; k < 4; ++k) { W0[k] = Wn[k * 128 + lane]; W1[k] = Wn[k * 128 + 64 + lane]; }
  float c_b0 = bn[lane],    c_b1 = bn[64 + lane];
  float c_g0 = gn[lane],    c_g1 = gn[64 + lane];
  float c_e0 = betan[lane], c_e1 = betan[64 + lane];

  for (int t = 0; t < 64; ++t) {
    int node = base + t;
    if (node >= N) break;
    float bf0 = bcastf(f0, t), bf1 = bcastf(f1, t);
    float bf2 = bcastf(f2, t), bf3 = bcastf(f3, t);
    float bm  = bcastf(mmean, t), br = bcastf(rstd, t);
    float y0 = c_b0, y1 = c_b1;
    y0 = fmaf(bf0, W0[0], y0); y0 = fmaf(bf1, W0[1], y0);
    y0 = fmaf(bf2, W0[2], y0); y0 = fmaf(bf3, W0[3], y0);
    y1 = fmaf(bf0, W1[0], y1); y1 = fmaf(bf1, W1[1], y1);
    y1 = fmaf(bf2, W1[2], y1); y1 = fmaf(bf3, W1[3], y1);
    size_t ro = (size_t)node * 128;
    outV[ro + lane]      = (y0 - bm) * br * c_g0 + c_e0;
    outV[ro + 64 + lane] = (y1 - bm) * br * c_g1 + c_e1;
  }
}

// ---------- edge kernel ----------
__global__ __launch_bounds__(256) void edge_kernel(
    const float* __restrict__ X, const int* __restrict__ eidx,
    const float* __restrict__ We, const float* __restrict__ be,
    const float* __restrict__ ge, const float* __restrict__ betae,
    const float* __restrict__ Qws, const int* __restrict__ validws,
    const float* __restrict__ Ge, const float* __restrict__ abarE,
    float* __restrict__ outE, int N, int E)
{
  int lane = threadIdx.x & 63;
  int wave = threadIdx.x >> 6;
  int base = blockIdx.x * 256 + wave * 64;
  int e = base + lane;
  int ec = (e < E) ? e : (E - 1);

  int s = eidx[ec];
  int t = eidx[E + ec];

  float Xs0 = X[3*s], Xs1 = X[3*s+1], Xs2 = X[3*s+2];
  float Xt0 = X[3*t], Xt1 = X[3*t+1], Xt2 = X[3*t+2];

  float Qs[9], Qt[9];
  #pragma unroll
  for (int k = 0; k < 9; ++k) { Qs[k] = Qws[(size_t)s * 9 + k]; Qt[k] = Qws[(size_t)t * 9 + k]; }
  int ok = validws[s] & validws[t];

  // R = Qt^T * Qs ;  R[i][k] = sum_j Qt[3j+i]*Qs[3j+k]
  float R[9];
  #pragma unroll
  for (int i = 0; i < 3; ++i) {
    #pragma unroll
    for (int k = 0; k < 3; ++k) {
      R[3*i+k] = Qt[i] * Qs[k] + Qt[3+i] * Qs[3+k] + Qt[6+i] * Qs[6+k];
    }
  }

  float Rxx = R[0], Ryy = R[4], Rzz = R[8];
  float m0 = 0.5f * sqrtf(fabsf(1.f + Rxx - Ryy - Rzz));
  float m1 = 0.5f * sqrtf(fabsf(1.f - Rxx + Ryy - Rzz));
  float m2 = 0.5f * sqrtf(fabsf(1.f - Rxx - Ryy + Rzz));
  float s0 = sgnf(R[7] - R[5]);   // R21 - R12
  float s1 = sgnf(R[2] - R[6]);   // R02 - R20
  float s2 = sgnf(R[3] - R[1]);   // R10 - R01
  float w  = 0.5f * sqrtf(fmaxf(1.f + Rxx + Ryy + Rzz, 0.f));
  float q0 = s0 * m0, q1 = s1 * m1, q2 = s2 * m2;
  float qn = fmaxf(sqrtf(q0*q0 + q1*q1 + q2*q2 + w*w), 1e-12f);
  float qinv = 1.0f / qn;
  float msk = ok ? 1.f : 0.f;

  float f[23];
  f[0] = q0 * qinv * msk; f[1] = q1 * qinv * msk;
  f[2] = q2 * qinv * msk; f[3] = w  * qinv * msk;

  float dx = Xs0 - Xt0, dy = Xs1 - Xt1, dz = Xs2 - Xt2;
  float d2 = dx*dx + dy*dy + dz*dz;
  float dist = sqrtf(d2 + 1e-6f);
  #pragma unroll
  for (int k = 0; k < 16; ++k) {
    float u = (dist - (float)k * (20.0f / 15.0f)) * 0.8f;
    f[4 + k] = __expf(-u * u);
  }
  float dn = fmaxf(sqrtf(d2), 1e-12f);
  float rinv = 1.0f / dn;
  float ux = dx * rinv, uy = dy * rinv, uz = dz * rinv;
  // direct = Qt^T * u  (Qt rows are zero when tgt invalid -> already masked)
  f[20] = Qt[0]*ux + Qt[3]*uy + Qt[6]*uz;
  f[21] = Qt[1]*ux + Qt[4]*uy + Qt[7]*uz;
  f[22] = Qt[2]*ux + Qt[5]*uy + Qt[8]*uz;

  // analytic LN stats (fa = [f, 1]); Ge/abarE loads are wave-uniform -> scalar path
  float mmean = abarE[23];
  #pragma unroll
  for (int k = 0; k < 23; ++k) mmean = fmaf(f[k], abarE[k], mmean);
  float E2 = 0.f;
  #pragma unroll
  for (int ii = 0; ii < 24; ++ii) {
    float fi = (ii < 23) ? f[ii] : 1.0f;
    float ti = 0.f;
    #pragma unroll
    for (int jj = 0; jj < 24; ++jj) {
      float fj = (jj < 23) ? f[jj] : 1.0f;
      ti = fmaf(Ge[ii * 24 + jj], fj, ti);
    }
    E2 = fmaf(fi, ti, E2);
  }
  float var  = fmaxf(E2 - mmean * mmean, 0.f);
  float rstd = rsqrtf(var + 1e-5f);

  // per-lane W columns (persist in VGPRs across the broadcast loop)
  float W0[23], W1[23];
  #pragma unroll
  for (int k = 0; k < 23; ++k) { W0[k] = We[k * 128 + lane]; W1[k] = We[k * 128 + 64 + lane]; }
  float c_b0 = be[lane],    c_b1 = be[64 + lane];
  float c_g0 = ge[lane],    c_g1 = ge[64 + lane];
  float c_e0 = betae[lane], c_e1 = betae[64 + lane];

  for (int tt = 0; tt < 64; ++tt) {
    int ee = base + tt;
    if (ee >= E) break;
    float bm = bcastf(mmean, tt), br = bcastf(rstd, tt);
    float y0 = c_b0, y1 = c_b1;
    #pragma unroll
    for (int k = 0; k < 23; ++k) {
      float bf = bcastf(f[k], tt);
      y0 = fmaf(bf, W0[k], y0);
      y1 = fmaf(bf, W1[k], y1);
    }
    size_t ro = (size_t)ee * 128;
    outE[ro + lane]      = (y0 - bm) * br * c_g0 + c_e0;
    outE[ro + 64 + lane] = (y1 - bm) * br * c_g1 + c_e1;
  }
}

// ---------- launcher ----------
extern "C" void kernel_launch(void* const* d_in, const int* in_sizes, int n_in,
                              void* d_out, int out_size, void* d_ws, size_t ws_size,
                              hipStream_t stream)
{
  const float* X     = (const float*)d_in[0];
  const int*   batch = (const int*)  d_in[1];
  const int*   eidx  = (const int*)  d_in[2];
  const float* Wn    = (const float*)d_in[3];
  const float* bn    = (const float*)d_in[4];
  const float* gn    = (const float*)d_in[5];
  const float* betan = (const float*)d_in[6];
  const float* We    = (const float*)d_in[7];
  const float* be    = (const float*)d_in[8];
  const float* ge    = (const float*)d_in[9];
  const float* betae = (const float*)d_in[10];

  int N = in_sizes[0] / 3;
  int E = in_sizes[2] / 2;

  float* ws      = (float*)d_ws;
  float* Qws     = ws;                                  // N*9 floats
  int*   validws = (int*)(ws + (size_t)N * 9);          // N ints
  float* Ge      = ws + (size_t)N * 9 + N;              // 576
  float* abarE   = Ge + 576;                            // 24
  float* Gn      = abarE + 24;                          // 25
  float* abarN   = Gn + 25;                             // 5

  float* outV = (float*)d_out;
  float* outE = outV + (size_t)N * 128;

  hipLaunchKernelGGL(setup_gram, dim3(1), dim3(640), 0, stream,
                     Wn, bn, We, be, Ge, abarE, Gn, abarN);

  int nblocks = (N + 255) / 256;
  hipLaunchKernelGGL(node_kernel, dim3(nblocks), dim3(256), 0, stream,
                     X, batch, Wn, bn, gn, betan, Gn, abarN, Qws, validws, outV, N);

  int eblocks = (E + 255) / 256;
  hipLaunchKernelGGL(edge_kernel, dim3(eblocks), dim3(256), 0, stream,
                     X, eidx, We, be, ge, betae, Qws, validws, Ge, abarE, outE, N, E);
}